// Round 8
// baseline (192.098 us; speedup 1.0000x reference)
//
#include <hip/hip_runtime.h>
#include <math.h>

// VP-SDE Euler-Maruyama forward diffusion (fp32).
// out[0] = x; out[t+1] = a_t * out[t] + b_t * noise[t],  t = 0..99
// beta_t = 0.1 + (t/100)*19.9; a_t = 1 - 0.5*beta_t/100; b_t = sqrt(beta_t)/10.
//
// Ladder: R1 199.8 (naive) -> R4 178.5 (2-buf ping-pong, nt ld/st)
// -> R5 183.1 (cached st, confounded) -> R6 192.1 (LDS-DMA; FETCH halved but
// slower) -> R7 190.5 (cached ld on R4: slower).
// Conclusion: latency/MLP-bound, not BW-bound (halving HBM fetch made it
// SLOWER; bytes-in-flight model matches R4's 2.26 TB/s read rate exactly).
// R8: 4 rotating register buffers -> 15-20 nt loads in flight per wave
// (~5 KB/CU read-bytes in flight), running-pointer addressing (no 64-bit
// muls in the hot loop), nt loads + nt stores.

#define S_STEPS 100
#define U 5                     // timesteps per window
#define NW (S_STEPS / U)        // 20 windows
#define DEPTH 4                 // buffers / windows in flight

typedef float f32x4 __attribute__((ext_vector_type(4)));

__global__ __launch_bounds__(256, 4) void vpsde_fwd_kernel(
    const f32x4* __restrict__ x,
    const f32x4* __restrict__ noise,
    f32x4* __restrict__ out,
    int ne4)  // float4 elements per timestep plane
{
    __shared__ float s_a[S_STEPS];
    __shared__ float s_b[S_STEPS];

    const int tid = threadIdx.x;
    if (tid < S_STEPS) {
        const float dt = 0.01f;
        float nt_ = (float)tid * dt;          // (t-1)/S for t=1..S
        float beta = 0.1f + nt_ * 19.9f;
        s_a[tid] = 1.0f - 0.5f * beta * dt;
        s_b[tid] = sqrtf(beta) * 0.1f;        // sqrt(beta)*sqrt(dt)
    }
    __syncthreads();

    const int idx = blockIdx.x * blockDim.x + tid;
    if (idx >= ne4) return;

    const size_t wstr = (size_t)U * ne4;      // one window of planes

    const f32x4* gl = noise + idx;            // running load pointer
    f32x4*       st = out + idx + ne4;        // running store ptr (out[t+1])

    f32x4 xv = x[idx];
    __builtin_nontemporal_store(xv, out + idx);   // out[0] = x

    f32x4 A[U], B[U], C[U], D[U];
    int tt = 0;                                // current window's first t

    auto loadw = [&](f32x4* buf) {             // 5 nt loads, bump gl
        #pragma unroll
        for (int k = 0; k < U; ++k)
            buf[k] = __builtin_nontemporal_load(gl + (size_t)k * ne4);
        gl += wstr;
    };
    auto consume = [&](const f32x4* buf) {     // 5 fma + nt stores, bump tt/st
        #pragma unroll
        for (int k = 0; k < U; ++k) {
            const float a = s_a[tt + k];
            const float b = s_b[tt + k];
            xv = a * xv + b * buf[k];
            __builtin_nontemporal_store(xv, st + (size_t)k * ne4);
        }
        tt += U;
        st += wstr;
    };

    // Prologue: DEPTH windows in flight (20 loads outstanding).
    loadw(A); loadw(B); loadw(C); loadw(D);

    // 4 cycles x 4 windows = 16 consumed, windows 4..19 loaded on the fly.
    #pragma unroll 1
    for (int cyc = 0; cyc < (NW / DEPTH) - 1; ++cyc) {
        consume(A); loadw(A);
        consume(B); loadw(B);
        consume(C); loadw(C);
        consume(D); loadw(D);
    }
    // Epilogue: consume the last DEPTH windows (16..19).
    consume(A); consume(B); consume(C); consume(D);
}

extern "C" void kernel_launch(void* const* d_in, const int* in_sizes, int n_in,
                              void* d_out, int out_size, void* d_ws, size_t ws_size,
                              hipStream_t stream) {
    const float* x     = (const float*)d_in[0];   // (64,256,64)
    const float* noise = (const float*)d_in[1];   // (100,64,256,64)
    float* out         = (float*)d_out;           // (101,64,256,64)

    const int ne  = in_sizes[0];       // 1,048,576 elements per timestep
    const int ne4 = ne / 4;            // 262,144 float4 per timestep

    const int block = 256;
    const int grid  = (ne4 + block - 1) / block;  // 1024 blocks (4/CU)

    vpsde_fwd_kernel<<<grid, block, 0, stream>>>(
        (const f32x4*)x, (const f32x4*)noise, (f32x4*)out, ne4);
}

// Round 9
// 177.764 us; speedup vs baseline: 1.0806x; 1.0806x over previous
//
#include <hip/hip_runtime.h>
#include <math.h>

// VP-SDE Euler-Maruyama forward diffusion (fp32).
// out[0] = x; out[t+1] = a_t * out[t] + b_t * noise[t],  t = 0..99
// beta_t = 0.1 + (t/100)*19.9; a_t = 1 - 0.5*beta_t/100; b_t = sqrt(beta_t)/10.
//
// Ladder: R1 199.8 naive | R4 178.5 (2-buf ping-pong, nt/nt, 16 waves/CU)
// | R5 183 (cached st) | R6 192 (LDS-DMA) | R7 190 (cached ld) | R8 192
// (4-buf: VMEM queue overflow).
// Diagnosis: m13 proves 1:1 R/W mix sustains 6.29 TB/s, so 4.53 isn't a
// mix wall; copy kernels differ from us in TLP. We're pinned at 16 waves/CU
// by 16 B/lane. R9: float2 per lane -> 2048 blocks -> 32 waves/CU (chip max),
// same proven nt/nt ping-pong. VGPR ~45 << 64 so full occupancy stands.

#define S_STEPS 100
#define U 5                    // timesteps per window
#define NW (S_STEPS / U)       // 20 windows (even -> clean ping-pong)

typedef float f32x2 __attribute__((ext_vector_type(2)));

__global__ __launch_bounds__(256) void vpsde_fwd_kernel(
    const f32x2* __restrict__ x,
    const f32x2* __restrict__ noise,
    f32x2* __restrict__ out,
    int ne2)  // float2 elements per timestep plane
{
    __shared__ float s_a[S_STEPS];
    __shared__ float s_b[S_STEPS];

    const int tid = threadIdx.x;
    if (tid < S_STEPS) {
        const float dt = 0.01f;
        float nt_ = (float)tid * dt;          // (t-1)/S for t=1..S
        float beta = 0.1f + nt_ * 19.9f;
        s_a[tid] = 1.0f - 0.5f * beta * dt;
        s_b[tid] = sqrtf(beta) * 0.1f;        // sqrt(beta)*sqrt(dt)
    }
    __syncthreads();

    const int idx = blockIdx.x * blockDim.x + tid;
    if (idx >= ne2) return;

    const f32x2* np_ = noise + idx;
    f32x2* op_ = out + idx;

    f32x2 xv = x[idx];
    __builtin_nontemporal_store(xv, op_);     // out[0] = x

    f32x2 A[U], B[U];

    auto loadw = [&](f32x2* buf, int w0) {
        #pragma unroll
        for (int k = 0; k < U; ++k)
            buf[k] = __builtin_nontemporal_load(np_ + (size_t)(w0 + k) * ne2);
    };
    auto consume = [&](const f32x2* buf, int w0) {
        #pragma unroll
        for (int k = 0; k < U; ++k) {
            const int t = w0 + k;
            const float a = s_a[t];
            const float b = s_b[t];
            xv = a * xv + b * buf[k];          // componentwise fma
            __builtin_nontemporal_store(xv, op_ + (size_t)(t + 1) * ne2);
        }
    };

    // Ping-pong software pipeline: window w+1's loads stay in flight while
    // window w is consumed.
    loadw(A, 0);
    for (int w = 0; w < NW; w += 2) {
        loadw(B, (w + 1) * U);                     // prefetch next window
        consume(A, w * U);
        if (w + 2 < NW) loadw(A, (w + 2) * U);     // prefetch window after next
        consume(B, (w + 1) * U);
    }
}

extern "C" void kernel_launch(void* const* d_in, const int* in_sizes, int n_in,
                              void* d_out, int out_size, void* d_ws, size_t ws_size,
                              hipStream_t stream) {
    const float* x     = (const float*)d_in[0];   // (64,256,64)
    const float* noise = (const float*)d_in[1];   // (100,64,256,64)
    float* out         = (float*)d_out;           // (101,64,256,64)

    const int ne  = in_sizes[0];       // 1,048,576 floats per timestep plane
    const int ne2 = ne / 2;            // 524,288 float2 per plane

    const int block = 256;
    const int grid  = (ne2 + block - 1) / block;  // 2048 blocks -> 8/CU

    vpsde_fwd_kernel<<<grid, block, 0, stream>>>(
        (const f32x2*)x, (const f32x2*)noise, (f32x2*)out, ne2);
}